// Round 8
// baseline (1383.443 us; speedup 1.0000x reference)
//
// TransformerDecoderBlock on MI355X (gfx950) — round 11: r10 minus the scratch bug.
// r10 post-mortem: WRITE_SIZE 759MB (r8: 33MB) with no global writes in the loop = SCRATCH.
// r9+r10 shared the PV_HALF *macro* with _Pragma unrolls over o[ds*8+QS0+qq]/al_[qq]/vr[4]
// (rule #20: runtime-indexed ext_vector arrays -> localMem); V path was innocent (r10 proved it:
// staging identical to r8, FETCH still 1.2GB). Fix: templated __forceinline__ pv_half<QS0> with
// normal #pragma unroll; vr held 16 regs -> transient 4 (re-read per qq, 16 b128/iter, still
// < r8's 32); al_[4] -> scalar. Everything else identical to r10 (d-sliced PV, P through LDS,
// K+V global_load_lds dbuf, causal 65-iter pairing, 2 barriers/iter, LDS 140KB).
#include <hip/hip_runtime.h>
#include <cstdint>
#include <cstddef>

#define NB 4
#define NS 4096
#define ND 512
#define NF 2048

typedef __bf16 bf16;
typedef __attribute__((ext_vector_type(8))) __bf16 bf16x8;
typedef __attribute__((ext_vector_type(4))) __bf16 bf16x4;
typedef __attribute__((ext_vector_type(4))) float f32x4;

#define MFMA16(a, b, c) __builtin_amdgcn_mfma_f32_16x16x32_bf16((a), (b), (c), 0, 0, 0)

// Async global->LDS, 16B per lane. LDS dest is wave-uniform base; lane i lands at base+16*i.
__device__ __forceinline__ void async_copy16(void* lds, const void* g) {
  __builtin_amdgcn_global_load_lds(
      (__attribute__((address_space(1))) unsigned int*)(uintptr_t)g,
      (__attribute__((address_space(3))) unsigned int*)(unsigned)(uintptr_t)lds,
      16, 0, 0);
}

// V^T global k-swizzle: within each 32-k block, 8-elem chunk c of dim-row d is stored at
// chunk ((c + (d>>1)) & 3). Makes the attention PV ds_read_b128 conflict-free.
__device__ __forceinline__ int vswz_col(int c /*mult of 8 in [0,64)*/, int dloc) {
  return (c & ~31) | (((((c >> 3) & 3) + ((dloc >> 1) & 3)) & 3) << 3);
}

// ---------------- dtype detect ----------------
__global__ void k_detect(const unsigned short* __restrict__ x, unsigned* __restrict__ flag) {
  __shared__ int cnt;
  if (threadIdx.x == 0) cnt = 0;
  __syncthreads();
  int bad = 0;
  for (int i = threadIdx.x; i < 2048; i += 256) {
    unsigned e = (x[i] >> 7) & 0xFF;
    if (e < 100 || e > 140) bad++;
  }
  atomicAdd(&cnt, bad);
  __syncthreads();
  if (threadIdx.x == 0) *flag = (cnt > 200) ? 1u : 0u;  // 1 => inputs are f32
}

// ---------------- input normalization ----------------
__global__ void k_norm_bf16(const void* __restrict__ src, bf16* __restrict__ dst,
                            const unsigned* __restrict__ flag, int n) {
  int i = (blockIdx.x * 256 + threadIdx.x) * 8;
  if (i >= n) return;
  if (*flag) {
    const float* s = (const float*)src;
    float4 a = *(const float4*)(s + i);
    float4 c = *(const float4*)(s + i + 4);
    bf16x8 v;
    v[0] = (bf16)a.x; v[1] = (bf16)a.y; v[2] = (bf16)a.z; v[3] = (bf16)a.w;
    v[4] = (bf16)c.x; v[5] = (bf16)c.y; v[6] = (bf16)c.z; v[7] = (bf16)c.w;
    *(bf16x8*)(dst + i) = v;
  } else {
    *(uint4*)(dst + i) = *(const uint4*)((const bf16*)src + i);
  }
}

__global__ void k_norm_f32(const void* __restrict__ src, float* __restrict__ dst,
                           const unsigned* __restrict__ flag, int n) {
  int i = blockIdx.x * 256 + threadIdx.x;
  if (i >= n) return;
  dst[i] = (*flag) ? ((const float*)src)[i] : (float)((const bf16*)src)[i];
}

// ---------------- transpose [B][S][D] -> [B][D][S] (bf16), k-swizzled output ----------------
__global__ void k_transpose(const bf16* __restrict__ in, bf16* __restrict__ out) {
  __shared__ bf16 t[64][72];
  const int b = blockIdx.z, s0 = blockIdx.x * 64, d0 = blockIdx.y * 64;
  const int tid = threadIdx.x;
#pragma unroll
  for (int it = 0; it < 2; ++it) {
    int slot = it * 256 + tid;
    int r = slot >> 3, c = (slot & 7) * 8;
    *(bf16x8*)&t[r][c] = *(const bf16x8*)&in[((size_t)b * NS + s0 + r) * ND + d0 + c];
  }
  __syncthreads();
#pragma unroll
  for (int it = 0; it < 2; ++it) {
    int slot = it * 256 + tid;
    int r = slot >> 3, c = (slot & 7) * 8;  // r = local dim, c = local seq base
    bf16x8 v;
#pragma unroll
    for (int k = 0; k < 8; ++k) v[k] = t[c + k][r];
    *(bf16x8*)&out[((size_t)b * ND + d0 + r) * NS + s0 + vswz_col(c, r)] = v;
  }
}

// ---------------- PV helper: rescale + accumulate one 4-qslot group (static unroll) ----------
template <int QS0>
__device__ __forceinline__ void pv_half(f32x4 (&o)[32], const bf16* __restrict__ Pt,
                                        const float* __restrict__ alds,
                                        const bf16* __restrict__ Vs, int w, int quad, int l15,
                                        int vsw) {
  const bf16* Vb = Vs + (w * 64 + l15) * 32 + vsw;  // + ds*512
#pragma unroll
  for (int qq = 0; qq < 4; ++qq) {
    const float al = alds[(QS0 + qq) * 16 + l15];
    if (__ballot(al < 0.99999f)) {
#pragma unroll
      for (int ds = 0; ds < 4; ++ds)
#pragma unroll
        for (int r2 = 0; r2 < 4; ++r2) o[ds * 8 + QS0 + qq][r2] *= al;
    }
    bf16x8 pb = *(const bf16x8*)&Pt[((QS0 + qq) * 16 + l15) * 32 + quad * 8];
    __builtin_amdgcn_s_setprio(1);
#pragma unroll
    for (int ds = 0; ds < 4; ++ds) {
      bf16x8 vr = *(const bf16x8*)&Vb[ds * 512];
      o[ds * 8 + QS0 + qq] = MFMA16(vr, pb, o[ds * 8 + QS0 + qq]);
    }
    __builtin_amdgcn_s_setprio(0);
  }
}

// ---------------- flash attention — r11 core ----------------
// Grid: 256 blocks x 512 threads (8 waves). slot = blkid&7 -> (b = slot>>1, z = slot&1).
// Cross: block j owns q-rows [128j, 128j+128); wave w softmax-owns 16 q (slot w*16).
// Causal: block j owns lo rows [64j, 64j+64) (waves 0-3) + hi rows [4032-64j, 4096-64j)
// (waves 4-7); worklist nLo=j+1 lo tiles then 64-j hi tiles (z halves each) = 65 iters/block.
// PV d-sliced: every wave accumulates O^T[d = 64w..64w+64) x all (active) block q, V from LDS.
template <bool CAUSAL>
__global__ __launch_bounds__(512, 2) void k_attn11(const bf16* __restrict__ Q,
                                                   const bf16* __restrict__ Km,
                                                   const bf16* __restrict__ Vt,
                                                   bf16* __restrict__ O0, bf16* __restrict__ O1,
                                                   float2* __restrict__ ml) {
  __shared__ __align__(16) char smem[140288];
  bf16* KV = (bf16*)smem;                     // 2 x { Ks [32][512] 32KB + Vs [512][32] 32KB }
  bf16* Pt = (bf16*)(smem + 131072);          // P^T [128 qslot][32 k] = 8192 B
  float* alds = (float*)(smem + 139264);      // alpha[128]
  float* llds = (float*)(smem + 139776);      // l[128]

  const int tid = threadIdx.x;
  const int w = tid >> 6, lane = tid & 63, quad = lane >> 4, l15 = lane & 15;
  const int slot = blockIdx.x & 7;
  const int b = slot >> 1;
  const int z = slot & 1;
  const int j = (int)(blockIdx.x >> 3);

  // per-wave softmax-owned q-row base + worklist shape
  int qwb, nLo, n;
  if (CAUSAL) {
    nLo = j + 1;
    n = 65;
    qwb = (w < 4) ? (64 * j + w * 16) : (4032 - 64 * j + (w - 4) * 16);
  } else {
    nLo = 1 << 30;
    n = 64;
    qwb = j * 128 + w * 16;
  }
  const int nHi = 64 - j;

  const bf16* Kg = Km + (size_t)b * NS * ND;
  const bf16* Vg = Vt + (size_t)b * ND * NS;

  auto ktOf = [&](int i) -> int {
    if (!CAUSAL) return z * 64 + i;
    return (i < nLo) ? (z * nLo + i) : (z * nHi + (i - nLo));
  };

  // ---- Q fragments in registers, pre-scaled by 1/sqrt(D) ----
  const bf16* Qg = Q + ((size_t)b * NS + qwb + l15) * ND;
  bf16x8 qf[16];
#pragma unroll
  for (int s = 0; s < 16; ++s) qf[s] = *(const bf16x8*)&Qg[s * 32 + quad * 8];
#pragma unroll
  for (int s = 0; s < 16; ++s)
#pragma unroll
    for (int jj = 0; jj < 8; ++jj) qf[s][jj] = (bf16)((float)qf[s][jj] * 0.044194173824159216f);

  // O^T accumulator, d-sliced: o[ds*8+qs] -> (d = w*64 + ds*16 + quad*4 + r, q = qs*16 + l15)
  f32x4 o[32];
#pragma unroll
  for (int i = 0; i < 32; ++i) o[i] = (f32x4){0.f, 0.f, 0.f, 0.f};

  float m = -1e30f, l = 0.f;  // per-lane softmax state, q = qwb + l15 (replicated across quads)

  const int vsw = ((quad + ((l15 >> 1) & 3)) & 3) * 8;  // swizzled V chunk offset (elements)

  // stage K tile [32][512] (XOR-swizzled rows) + V^T tile [512][32] (global pre-swizzled)
  auto STAGE = [&](bf16* base, int k0) {
#pragma unroll
    for (int i2 = 0; i2 < 4; ++i2) {
      const int r = w * 4 + i2;
      const int g = (lane & ~7) | ((lane ^ r) & 7);
      async_copy16(base + r * 512, Kg + (size_t)(k0 + r) * ND + g * 8);
    }
#pragma unroll
    for (int i2 = 0; i2 < 4; ++i2) {
      const int d0 = (w * 4 + i2) * 16;
      async_copy16(base + 16384 + d0 * 32, Vg + (size_t)(d0 + (lane >> 2)) * NS + k0 + (lane & 3) * 8);
    }
  };

  int buf = 0;
  STAGE(KV, ktOf(0) * 32);
  __syncthreads();  // prologue staging drained

  for (int i = 0; i < n; ++i) {
    const int k0 = ktOf(i) * 32;
    bf16* Ks = KV + buf * 32768;
    bf16* Vs = Ks + 16384;

    // ---- prefetch next tile (K+V) into the other buffer; lands during QK^T ----
    if (i + 1 < n) STAGE(KV + (buf ^ 1) * 32768, ktOf(i + 1) * 32);

    const bool qactive = !CAUSAL || ((w >= 4) == (i >= nLo));
    if (qactive) {
      // ---- S^T = K * Q^T ----
      f32x4 sa0 = (f32x4){0.f, 0.f, 0.f, 0.f};
      f32x4 sa1 = (f32x4){0.f, 0.f, 0.f, 0.f};
      __builtin_amdgcn_s_setprio(1);
#pragma unroll
      for (int s = 0; s < 16; ++s) {
        const int lc = s * 4 + quad;
        const int swz = ((lc & ~7) | ((lc ^ l15) & 7)) * 8;
        bf16x8 a0 = *(const bf16x8*)&Ks[l15 * 512 + swz];
        bf16x8 a1 = *(const bf16x8*)&Ks[(16 + l15) * 512 + swz];
        sa0 = MFMA16(a0, qf[s], sa0);
        sa1 = MFMA16(a1, qf[s], sa1);
      }
      __builtin_amdgcn_s_setprio(0);

      // ---- online softmax (wave-local; lane's q-row = qwb + l15) ----
      float sv[8];
      {
        const int qrow = qwb + l15;
        const bool needMask = CAUSAL && (k0 + 31 > qwb);
#pragma unroll
        for (int kt2 = 0; kt2 < 2; ++kt2)
#pragma unroll
          for (int r = 0; r < 4; ++r) {
            float s = (kt2 == 0) ? sa0[r] : sa1[r];
            if (needMask) {
              int key = k0 + kt2 * 16 + quad * 4 + r;
              if (key > qrow) s = -1e30f;
            }
            sv[kt2 * 4 + r] = s;
          }
      }
      float tm = sv[0];
#pragma unroll
      for (int i2 = 1; i2 < 8; ++i2) tm = fmaxf(tm, sv[i2]);
      tm = fmaxf(tm, __shfl_xor(tm, 16));
      tm = fmaxf(tm, __shfl_xor(tm, 32));
      const float mn = fmaxf(m, tm);
      const float alpha = __expf(m - mn);
      m = mn;
      float pf[8];
      float ts = 0.f;
#pragma unroll
      for (int i2 = 0; i2 < 8; ++i2) { pf[i2] = __expf(sv[i2] - mn); ts += pf[i2]; }
      ts += __shfl_xor(ts, 16);
      ts += __shfl_xor(ts, 32);
      l = l * alpha + ts;

      // ---- publish P^T[qslot][k] + alpha ----
      bf16x4 pA, pB;
#pragma unroll
      for (int r2 = 0; r2 < 4; ++r2) { pA[r2] = (bf16)pf[r2]; pB[r2] = (bf16)pf[4 + r2]; }
      *(bf16x4*)&Pt[(w * 16 + l15) * 32 + quad * 4] = pA;        // k = quad*4..+4
      *(bf16x4*)&Pt[(w * 16 + l15) * 32 + 16 + quad * 4] = pB;   // k = 16+quad*4..+4
      if (quad == 0) alds[w * 16 + l15] = alpha;
    }
    __syncthreads();  // P + alpha visible (also drains K/V prefetch into buf^1)

    // ---- rescale + PV over active q half/full (V from LDS, transient regs) ----
    if (CAUSAL) {
      if (i >= nLo) pv_half<4>(o, Pt, alds, Vs, w, quad, l15, vsw);
      else pv_half<0>(o, Pt, alds, Vs, w, quad, l15, vsw);
    } else {
      pv_half<0>(o, Pt, alds, Vs, w, quad, l15, vsw);
      pv_half<4>(o, Pt, alds, Vs, w, quad, l15, vsw);
    }
    __syncthreads();  // Pt/Vs reads done before next overwrite
    buf ^= 1;
  }

  // ---- epilogue: exchange l, normalize, stage per-half [64][520] in LDS, coalesced write ----
  if (quad == 0) {
    llds[w * 16 + l15] = l;
    ml[((size_t)z * NB + b) * NS + qwb + l15] = make_float2(m, l);
  }
  __syncthreads();
  bf16* EP = KV;  // overlay (66,560 B < KV region)
  bf16* Og = (z ? O1 : O0);
#pragma unroll
  for (int half = 0; half < 2; ++half) {
#pragma unroll
    for (int qq = 0; qq < 4; ++qq) {
      const int qs = half * 4 + qq;
      const float invl = 1.f / llds[qs * 16 + l15];
#pragma unroll
      for (int ds = 0; ds < 4; ++ds) {
        bf16x4 v;
#pragma unroll
        for (int r2 = 0; r2 < 4; ++r2) v[r2] = (bf16)(o[ds * 8 + qs][r2] * invl);
        *(bf16x4*)&EP[(qs * 16 + l15 - half * 64) * 520 + w * 64 + ds * 16 + quad * 4] = v;
      }
    }
    __syncthreads();
#pragma unroll
    for (int r2 = 0; r2 < 8; ++r2) {
      const int row = w * 8 + r2;
      int qg;
      if (CAUSAL) qg = (half == 0) ? (64 * j + row) : (4032 - 64 * j + row);
      else qg = j * 128 + half * 64 + row;
      *(bf16x8*)&Og[((size_t)b * NS + qg) * ND + lane * 8] = *(const bf16x8*)&EP[row * 520 + lane * 8];
    }
    __syncthreads();
  }
}

// ---------------- merge two K-split partials: O0 = c0*O0 + c1*O1 ----------------
__global__ void k_merge(bf16* __restrict__ O0, const bf16* __restrict__ O1,
                        const float2* __restrict__ ml) {
  size_t i = ((size_t)blockIdx.x * 256 + threadIdx.x) * 8;
  int row = (int)(i >> 9);  // / 512
  float2 a = ml[row];
  float2 c = ml[(size_t)NB * NS + row];
  float M = fmaxf(a.x, c.x);
  float w0 = __expf(a.x - M) * a.y;
  float w1 = __expf(c.x - M) * c.y;
  float den = 1.f / (w0 + w1);
  float c0 = w0 * den, c1 = w1 * den;
  bf16x8 v0 = *(const bf16x8*)(O0 + i);
  bf16x8 v1 = *(const bf16x8*)(O1 + i);
  bf16x8 ov;
#pragma unroll
  for (int k = 0; k < 8; ++k) ov[k] = (bf16)(c0 * (float)v0[k] + c1 * (float)v1[k]);
  *(bf16x8*)(O0 + i) = ov;
}

// ---------------- NT GEMM: Out[M,N] = A[M,K] * W[N,K]^T (+bias)(+relu)(+res)(+LN stats) ----------------
template <int RES_MODE, bool HAS_BIAS, bool RELU, bool STATS>
__global__ __launch_bounds__(256) void k_gemm(const bf16* __restrict__ A, const bf16* __restrict__ W,
                                              const bf16* __restrict__ resid,
                                              const float* __restrict__ bias, bf16* __restrict__ Out,
                                              float* __restrict__ stats, int M, int N, int K,
                                              int rowOfs) {
  __shared__ bf16 As[128 * 64];
  __shared__ bf16 Ws[128 * 64];
  const int tid = threadIdx.x;
  const int w = tid >> 6, lane = tid & 63, quad = lane >> 4, l15 = lane & 15;
  const int m0 = blockIdx.x * 128, n0 = blockIdx.y * 128;
  const int wr = (w >> 1) * 64, wc = (w & 1) * 64;
  const int arow = lane >> 3, acol = (lane & 7) * 8;

  f32x4 acc[16];
#pragma unroll
  for (int i = 0; i < 16; ++i) acc[i] = (f32x4){0.f, 0.f, 0.f, 0.f};

  for (int k0 = 0; k0 < K; k0 += 64) {
    __syncthreads();
#pragma unroll
    for (int i = 0; i < 4; ++i) {
      const int rbase = (w * 4 + i) * 8 + arow;
      async_copy16(&As[(w * 4 + i) * 512], A + (size_t)(m0 + rbase) * K + k0 + acol);
      async_copy16(&Ws[(w * 4 + i) * 512], W + (size_t)(n0 + rbase) * K + k0 + acol);
    }
    __syncthreads();
#pragma unroll
    for (int s = 0; s < 2; ++s) {
      bf16x8 af[4], bw[4];
#pragma unroll
      for (int i = 0; i < 4; ++i) af[i] = *(const bf16x8*)&As[(wr + i * 16 + l15) * 64 + s * 32 + quad * 8];
#pragma unroll
      for (int jj = 0; jj < 4; ++jj) bw[jj] = *(const bf16x8*)&Ws[(wc + jj * 16 + l15) * 64 + s * 32 + quad * 8];
#pragma unroll
      for (int i = 0; i < 4; ++i)
#pragma unroll
        for (int jj = 0; jj < 4; ++jj) acc[i * 4 + jj] = MFMA16(af[i], bw[jj], acc[i * 4 + jj]);
    }
  }

  float lsum = 0.f, lsq = 0.f;
#pragma unroll
  for (int i = 0; i < 4; ++i)
#pragma unroll
    for (int jj = 0; jj < 4; ++jj)
#pragma unroll
      for (int r = 0; r < 4; ++r) {
        int row = m0 + wr + i * 16 + quad * 4 + r;
        int col = n0 + wc + jj * 16 + l15;
        float v = acc[i * 4 + jj][r];
        if (HAS_BIAS) v += bias[col];
        if (RELU) v = fmaxf(v, 0.f);
        if (RES_MODE == 2) v += (float)resid[(size_t)row * N + col];
        Out[(size_t)row * N + col] = (bf16)v;
        if (STATS) { lsum += v; lsq += v * v; }
      }

  if (STATS) {
    __syncthreads();
    float* red = (float*)As;
    red[tid] = lsum;
    red[256 + tid] = lsq;
    __syncthreads();
    for (int off = 128; off > 0; off >>= 1) {
      if (tid < off) { red[tid] += red[tid + off]; red[256 + tid] += red[256 + tid + off]; }
      __syncthreads();
    }
    if (tid == 0) {
      int bidx = (rowOfs + m0) >> 12;  // 4096 rows per batch
      atomicAdd(&stats[bidx * 2], red[0]);
      atomicAdd(&stats[bidx * 2 + 1], red[256]);
    }
  }
}

// ---------------- LayerNorm apply over (S,D) jointly per batch ----------------
template <bool FINAL>
__global__ void k_ln(const bf16* __restrict__ T, const float* __restrict__ stats,
                     const void* __restrict__ gp, const void* __restrict__ bp,
                     void* __restrict__ outp, const unsigned* __restrict__ flag) {
  const float invN = 1.f / 2097152.f;
  size_t i = ((size_t)(blockIdx.x * 256 + threadIdx.x)) * 8;
  int b = (int)(i >> 21);
  int sd = (int)(i & 2097151);
  float mu = stats[b * 2] * invN;
  float var = stats[b * 2 + 1] * invN - mu * mu;
  float rs = rsqrtf(var + 1e-5f);
  bool f32m = (*flag != 0);
  bf16x8 tv = *(const bf16x8*)(T + i);
  float gv[8], bv[8];
  if (f32m) {
    float4 a = *(const float4*)((const float*)gp + sd), c = *(const float4*)((const float*)gp + sd + 4);
    gv[0] = a.x; gv[1] = a.y; gv[2] = a.z; gv[3] = a.w; gv[4] = c.x; gv[5] = c.y; gv[6] = c.z; gv[7] = c.w;
    float4 e = *(const float4*)((const float*)bp + sd), f = *(const float4*)((const float*)bp + sd + 4);
    bv[0] = e.x; bv[1] = e.y; bv[2] = e.z; bv[3] = e.w; bv[4] = f.x; bv[5] = f.y; bv[6] = f.z; bv[7] = f.w;
  } else {
    bf16x8 g8 = *(const bf16x8*)((const bf16*)gp + sd);
    bf16x8 b8 = *(const bf16x8*)((const bf16*)bp + sd);
#pragma unroll
    for (int k = 0; k < 8; ++k) { gv[k] = (float)g8[k]; bv[k] = (float)b8[k]; }
  }
  float ov[8];
#pragma unroll
  for (int k = 0; k < 8; ++k) ov[k] = ((float)tv[k] - mu) * rs * gv[k] + bv[k];
  if (FINAL && f32m) {
    float4 o0 = {ov[0], ov[1], ov[2], ov[3]}, o1 = {ov[4], ov[5], ov[6], ov[7]};
    *(float4*)((float*)outp + i) = o0;
    *(float4*)((float*)outp + i + 4) = o1;
  } else {
    bf16x8 o8;
#pragma unroll
    for (int k = 0; k < 8; ++k) o8[k] = (bf16)ov[k];
    *(bf16x8*)((bf16*)outp + i) = o8;
  }
}

// ---------------- fused LayerNorm + transpose: X = LN(T), XT = X^T (k-swizzled) ----------------
__global__ void k_ln_t(const bf16* __restrict__ T, const float* __restrict__ stats,
                       const void* __restrict__ gp, const void* __restrict__ bp,
                       bf16* __restrict__ X, bf16* __restrict__ XT,
                       const unsigned* __restrict__ flag) {
  __shared__ bf16 t[64][72];
  const float invN = 1.f / 2097152.f;
  const int b = blockIdx.z, s0 = blockIdx.x * 64, d0 = blockIdx.y * 64;
  const int tid = threadIdx.x;
  const float mu = stats[b * 2] * invN;
  const float var = stats[b * 2 + 1] * invN - mu * mu;
  const float rs = rsqrtf(var + 1e-5f);
  const bool f32m = (*flag != 0);
#pragma unroll
  for (int it = 0; it < 2; ++it) {
    int slot = it * 256 + tid;
    int r = slot >> 3, c = (slot & 7) * 8;
    size_t idx = ((size_t)b * NS + s0 + r) * ND + d0 + c;
    size_t pidx = (size_t)(s0 + r) * ND + d0 + c;
    bf16x8 tv = *(const bf16x8*)&T[idx];
    float gv[8], bv[8];
    if (f32m) {
      float4 a = *(const float4*)((const float*)gp + pidx), cc = *(const float4*)((const float*)gp + pidx + 4);
      gv[0] = a.x; gv[1] = a.y; gv[2] = a.z; gv[3] = a.w; gv[4] = cc.x; gv[5] = cc.y; gv[6] = cc.z; gv[7] = cc.w;
      float4 e = *(const float4*)((const float*)bp + pidx), f = *(const float4*)((const float*)bp + pidx + 4);
      bv[0] = e.x; bv[1] = e.y; bv[2] = e.z; bv[3] = e.w; bv[4] = f.x; bv[5] = f.y; bv[6] = f.z; bv[7] = f.w;
    } else {
      bf16x8 g8 = *(const bf16x8*)((const bf16*)gp + pidx);
      bf16x8 b8 = *(const bf16x8*)((const bf16*)bp + pidx);
#pragma unroll
      for (int k = 0; k < 8; ++k) { gv[k] = (float)g8[k]; bv[k] = (float)b8[k]; }
    }
    bf16x8 ov;
#pragma unroll
    for (int k = 0; k < 8; ++k) ov[k] = (bf16)(((float)tv[k] - mu) * rs * gv[k] + bv[k]);
    *(bf16x8*)&X[idx] = ov;
    *(bf16x8*)&t[r][c] = ov;
  }
  __syncthreads();
#pragma unroll
  for (int it = 0; it < 2; ++it) {
    int slot = it * 256 + tid;
    int r = slot >> 3, c = (slot & 7) * 8;  // r = local dim, c = local seq base
    bf16x8 v;
#pragma unroll
    for (int k = 0; k < 8; ++k) v[k] = t[c + k][r];
    *(bf16x8*)&XT[((size_t)b * ND + d0 + r) * NS + s0 + vswz_col(c, r)] = v;
  }
}

// ---------------- launch ----------------
extern "C" void kernel_launch(void* const* d_in, const int* in_sizes, int n_in, void* d_out,
                              int out_size, void* d_ws, size_t ws_size, hipStream_t stream) {
  (void)in_sizes; (void)n_in; (void)out_size;
  const void* x_raw = d_in[0];
  const void* enc_raw = d_in[1];
  const void* Wo1_raw = d_in[2];
  const void* Wo2_raw = d_in[3];
  const void* g1_raw = d_in[4];
  const void* bb1_raw = d_in[5];
  const void* g2_raw = d_in[6];
  const void* bb2_raw = d_in[7];
  const void* W1_raw = d_in[8];
  const void* bias1_raw = d_in[9];
  const void* W2_raw = d_in[10];
  const void* bias2_raw = d_in[11];

  char* w = (char*)d_ws;
  unsigned* flag = (unsigned*)(w + 0);
  float* stats = (float*)(w + 16);  // 3 stages x [B][2]
  float* b1f = (float*)(w + 1024);
  float* b2f = (float*)(w + 1024 + 8192);
  size_t off = 16384;
  const size_t nBSD = (size_t)NB * NS * ND;
  bf16* Wo1b = (bf16*)(w + off); off += (size_t)ND * ND * 2;
  bf16* Wo2b = (bf16*)(w + off); off += (size_t)ND * ND * 2;
  bf16* W1b = (bf16*)(w + off); off += (size_t)NF * ND * 2;
  bf16* W2b = (bf16*)(w + off); off += (size_t)ND * NF * 2;
  bf16* xb = (bf16*)(w + off); off += nBSD * 2;   // x bf16, later enc
  bf16* Ab = (bf16*)(w + off); off += nBSD * 2;
  bf16* Tb = (bf16*)(w + off); off += nBSD * 2;
  bf16* X1b = (bf16*)(w + off); off += nBSD * 2;
  bf16* Hb = (bf16*)(w + off);  // FFN hidden; attn partial-1 + ml earlier
  const size_t hbFull = (size_t)NB * NS * NF * 2;  // 64 MB (full-M FFN)
  const size_t hbHalf = hbFull / 2;                // 32 MB (2-chunk FFN)
  const bool ffnFull = (ws_size >= off + hbFull);
  if (!ffnFull && ws_size < off + hbHalf) return;

  bf16* O1b = Hb;                                 // partial-1 region (Hb dead until FFN)
  float2* mlb = (float2*)((char*)Hb + nBSD * 2);  // 2*B*S float2 = 256 KB

  hipMemsetAsync(stats, 0, 24 * sizeof(float), stream);
  k_detect<<<1, 256, 0, stream>>>((const unsigned short*)x_raw, flag);

  k_norm_bf16<<<(int)(nBSD / 2048), 256, 0, stream>>>(x_raw, xb, flag, (int)nBSD);
  k_norm_bf16<<<(ND * ND) / 2048, 256, 0, stream>>>(Wo1_raw, Wo1b, flag, ND * ND);
  k_norm_bf16<<<(ND * ND) / 2048, 256, 0, stream>>>(Wo2_raw, Wo2b, flag, ND * ND);
  k_norm_bf16<<<(NF * ND) / 2048, 256, 0, stream>>>(W1_raw, W1b, flag, NF * ND);
  k_norm_bf16<<<(NF * ND) / 2048, 256, 0, stream>>>(W2_raw, W2b, flag, ND * NF);
  k_norm_f32<<<8, 256, 0, stream>>>(bias1_raw, b1f, flag, NF);
  k_norm_f32<<<2, 256, 0, stream>>>(bias2_raw, b2f, flag, ND);

  // 1) causal self-attention + Wo1 + residual(x) + LN1 (fused with transpose for cross-attn V)
  k_transpose<<<dim3(NS / 64, ND / 64, NB), 256, 0, stream>>>(xb, Tb);  // x^T (swizzled) as V
  k_attn11<true><<<256, 512, 0, stream>>>(xb, xb, Tb, Ab, O1b, mlb);
  k_merge<<<(int)(nBSD / 2048), 256, 0, stream>>>(Ab, O1b, mlb);
  k_gemm<2, false, false, true><<<dim3(128, 4), 256, 0, stream>>>(Ab, Wo1b, xb, nullptr, Tb,
                                                                  stats + 0, NB * NS, ND, ND, 0);
  k_ln_t<<<dim3(NS / 64, ND / 64, NB), 256, 0, stream>>>(Tb, stats + 0, g1_raw, bb1_raw, X1b, Ab,
                                                         flag);  // X1 -> X1b, X1^T (swizzled) -> Ab
  k_norm_bf16<<<(int)(nBSD / 2048), 256, 0, stream>>>(enc_raw, xb, flag, (int)nBSD);  // xb := enc

  // 2) cross attention (q=k=enc, v=X1) + Wo2 + residual(X1) + LN2
  k_attn11<false><<<256, 512, 0, stream>>>(xb, xb, Ab, Tb, O1b, mlb);  // O0 -> Tb
  k_merge<<<(int)(nBSD / 2048), 256, 0, stream>>>(Tb, O1b, mlb);
  k_gemm<2, false, false, true><<<dim3(128, 4), 256, 0, stream>>>(Tb, Wo2b, X1b, nullptr, Ab,
                                                                  stats + 8, NB * NS, ND, ND, 0);
  k_ln<false><<<(int)(nBSD / 2048), 256, 0, stream>>>(Ab, stats + 8, g2_raw, bb2_raw, X1b, flag);
  // X1b now holds X2

  // 3) FFN + residual(X2) + LN (ln2 params). Full-M single pass if ws allows (FFN2: 2 blocks/CU).
  const int nChunk = ffnFull ? 1 : 2;
  const int rows = ffnFull ? (NB * NS) : 8192;
  for (int c = 0; c < nChunk; ++c) {
    size_t ro = (size_t)c * rows;
    k_gemm<0, true, true, false><<<dim3(rows / 128, 16), 256, 0, stream>>>(
        X1b + ro * ND, W1b, nullptr, b1f, Hb, nullptr, rows, NF, ND, 0);
    k_gemm<2, true, false, true><<<dim3(rows / 128, 4), 256, 0, stream>>>(
        Hb, W2b, X1b + ro * ND, b2f, Tb + ro * ND, stats + 16, rows, ND, NF, (int)ro);
  }
  k_ln<true><<<(int)(nBSD / 2048), 256, 0, stream>>>(Tb, stats + 16, g2_raw, bb2_raw, d_out, flag);
}

// Round 9
// 758.379 us; speedup vs baseline: 1.8242x; 1.8242x over previous
//
// TransformerDecoderBlock on MI355X (gfx950) — round 12: revert attn to r8 core (verified 216us,
// FETCH 28MB) + double-buffered k_gemm. r9-r11 d-sliced PV abandoned: 3 variants, persistent
// ~1GB FETCH anomaly (r11 fixed scratch WRITES 759->84MB but reads stayed) — unexplained = revert.
// k_gemm had r6-attn's serial-staging disease (barrier->stage->barrier->compute); applying the
// proven r7 transform: 2x LDS buffers, prefetch next k-step before compute, ONE barrier/step.
#include <hip/hip_runtime.h>
#include <cstdint>
#include <cstddef>

#define NB 4
#define NS 4096
#define ND 512
#define NF 2048

typedef __bf16 bf16;
typedef __attribute__((ext_vector_type(8))) __bf16 bf16x8;
typedef __attribute__((ext_vector_type(4))) __bf16 bf16x4;
typedef __attribute__((ext_vector_type(4))) float f32x4;

#define MFMA16(a, b, c) __builtin_amdgcn_mfma_f32_16x16x32_bf16((a), (b), (c), 0, 0, 0)

// Async global->LDS, 16B per lane. LDS dest is wave-uniform base; lane i lands at base+16*i.
__device__ __forceinline__ void async_copy16(void* lds, const void* g) {
  __builtin_amdgcn_global_load_lds(
      (__attribute__((address_space(1))) unsigned int*)(uintptr_t)g,
      (__attribute__((address_space(3))) unsigned int*)(unsigned)(uintptr_t)lds,
      16, 0, 0);
}

// V^T global k-swizzle: within each 32-k block, 8-elem chunk c of dim-row d is stored at
// chunk ((c + (d>>1)) & 3). Makes the attention PV ds_read_b128 conflict-free.
__device__ __forceinline__ int vswz_col(int c /*mult of 8 in [0,64)*/, int dloc) {
  return (c & ~31) | (((((c >> 3) & 3) + ((dloc >> 1) & 3)) & 3) << 3);
}

// ---------------- dtype detect ----------------
__global__ void k_detect(const unsigned short* __restrict__ x, unsigned* __restrict__ flag) {
  __shared__ int cnt;
  if (threadIdx.x == 0) cnt = 0;
  __syncthreads();
  int bad = 0;
  for (int i = threadIdx.x; i < 2048; i += 256) {
    unsigned e = (x[i] >> 7) & 0xFF;
    if (e < 100 || e > 140) bad++;
  }
  atomicAdd(&cnt, bad);
  __syncthreads();
  if (threadIdx.x == 0) *flag = (cnt > 200) ? 1u : 0u;  // 1 => inputs are f32
}

// ---------------- input normalization ----------------
__global__ void k_norm_bf16(const void* __restrict__ src, bf16* __restrict__ dst,
                            const unsigned* __restrict__ flag, int n) {
  int i = (blockIdx.x * 256 + threadIdx.x) * 8;
  if (i >= n) return;
  if (*flag) {
    const float* s = (const float*)src;
    float4 a = *(const float4*)(s + i);
    float4 c = *(const float4*)(s + i + 4);
    bf16x8 v;
    v[0] = (bf16)a.x; v[1] = (bf16)a.y; v[2] = (bf16)a.z; v[3] = (bf16)a.w;
    v[4] = (bf16)c.x; v[5] = (bf16)c.y; v[6] = (bf16)c.z; v[7] = (bf16)c.w;
    *(bf16x8*)(dst + i) = v;
  } else {
    *(uint4*)(dst + i) = *(const uint4*)((const bf16*)src + i);
  }
}

__global__ void k_norm_f32(const void* __restrict__ src, float* __restrict__ dst,
                           const unsigned* __restrict__ flag, int n) {
  int i = blockIdx.x * 256 + threadIdx.x;
  if (i >= n) return;
  dst[i] = (*flag) ? ((const float*)src)[i] : (float)((const bf16*)src)[i];
}

// ---------------- transpose [B][S][D] -> [B][D][S] (bf16), k-swizzled output ----------------
__global__ void k_transpose(const bf16* __restrict__ in, bf16* __restrict__ out) {
  __shared__ bf16 t[64][72];
  const int b = blockIdx.z, s0 = blockIdx.x * 64, d0 = blockIdx.y * 64;
  const int tid = threadIdx.x;
#pragma unroll
  for (int it = 0; it < 2; ++it) {
    int slot = it * 256 + tid;
    int r = slot >> 3, c = (slot & 7) * 8;
    *(bf16x8*)&t[r][c] = *(const bf16x8*)&in[((size_t)b * NS + s0 + r) * ND + d0 + c];
  }
  __syncthreads();
#pragma unroll
  for (int it = 0; it < 2; ++it) {
    int slot = it * 256 + tid;
    int r = slot >> 3, c = (slot & 7) * 8;  // r = local dim, c = local seq base
    bf16x8 v;
#pragma unroll
    for (int k = 0; k < 8; ++k) v[k] = t[c + k][r];
    *(bf16x8*)&out[((size_t)b * ND + d0 + r) * NS + s0 + vswz_col(c, r)] = v;
  }
}

// ---------------- flash attention — r8 core (verified): pipelined + causal diagonal pairing ----
// Grid: 256 blocks x 512 threads (8 waves). slot = blkid&7 -> (b = slot>>1, z = slot&1).
// Cross: q0 = (blkid>>3)*128, all 8 waves, 64 tiles (z-split of 128).
// Causal: j = blkid>>3 in [0,32); waves 0-3 own rows [64j, 64j+64), waves 4-7 own mirror rows
// [4032-64j, 4096-64j). Worklist: nLo = j+1 lo tiles then 64-j hi tiles = 65 iters for every j.
template <bool CAUSAL>
__global__ __launch_bounds__(512, 2) void k_attn8(const bf16* __restrict__ Q,
                                                  const bf16* __restrict__ Km,
                                                  const bf16* __restrict__ Vt,
                                                  bf16* __restrict__ O0, bf16* __restrict__ O1,
                                                  float2* __restrict__ ml) {
  __shared__ bf16 lds_[65536];  // 128 KB: 2 x { Ks [32 x 512] (32KB) + Vs [512 x 32] (32KB) }

  const int tid = threadIdx.x;
  const int w = tid >> 6, lane = tid & 63, quad = lane >> 4, l15 = lane & 15;
  const int slot = blockIdx.x & 7;
  const int b = slot >> 1;
  const int z = slot & 1;
  const int j = (int)(blockIdx.x >> 3);

  // per-wave q-row base + worklist shape
  int qwb, nLo, n;
  if (CAUSAL) {
    nLo = j + 1;                 // lo-group tiles for this z (z picks which half-range)
    n = 65;                      // (j+1) + (64-j), constant for all j
    qwb = (w < 4) ? (64 * j + w * 16) : (4032 - 64 * j + (w - 4) * 16);
  } else {
    nLo = 1 << 30;
    n = 64;
    qwb = j * 128 + w * 16;
  }
  const int nHi = 64 - j;  // causal hi-group tiles for this z

  const bf16* Kg = Km + (size_t)b * NS * ND;
  const bf16* Vg = Vt + (size_t)b * ND * NS;

  // worklist item -> k-tile index
  auto ktOf = [&](int i) -> int {
    if (!CAUSAL) return z * 64 + i;
    return (i < nLo) ? (z * nLo + i) : (z * nHi + (i - nLo));
  };

  // ---- Q fragments in registers, pre-scaled by 1/sqrt(D) ----
  const bf16* Qg = Q + ((size_t)b * NS + qwb + l15) * ND;
  bf16x8 qf[16];
#pragma unroll
  for (int s = 0; s < 16; ++s) qf[s] = *(const bf16x8*)&Qg[s * 32 + quad * 8];
#pragma unroll
  for (int s = 0; s < 16; ++s)
#pragma unroll
    for (int jj = 0; jj < 8; ++jj) qf[s][jj] = (bf16)((float)qf[s][jj] * 0.044194173824159216f);

  f32x4 o[32];  // O^T: o[dt] -> (d = dt*16 + quad*4 + r, q = l15)
#pragma unroll
  for (int i = 0; i < 32; ++i) o[i] = (f32x4){0.f, 0.f, 0.f, 0.f};

  float m = -1e30f, l = 0.f;  // per-lane, q = l15 (replicated across quads)

  const int laneA4 = ((((quad * 2) & 3) * 16) + l15) * 4;
  const int laneB4 = ((((quad * 2 + 1) & 3) * 16) + l15) * 4;
  const int vsw = ((quad + ((l15 >> 1) & 3)) & 3) * 8;  // swizzled V chunk offset (elements)

  // stage tile (K rows w*4..w*4+3 with XOR-swizzle source; V^T 16-d groups, chunk-linear)
  auto STAGE = [&](bf16* base, int k0) {
#pragma unroll
    for (int i = 0; i < 4; ++i) {
      const int r = w * 4 + i;
      const int g = (lane & ~7) | ((lane ^ r) & 7);
      async_copy16(base + r * 512, Kg + (size_t)(k0 + r) * ND + g * 8);
    }
#pragma unroll
    for (int i = 0; i < 4; ++i) {
      const int d0 = (w * 4 + i) * 16;
      async_copy16(base + 16384 + d0 * 32, Vg + (size_t)(d0 + (lane >> 2)) * NS + k0 + (lane & 3) * 8);
    }
  };

  int buf = 0;
  STAGE(lds_, ktOf(0) * 32);
  __syncthreads();  // prologue staging drained (compiler emits vmcnt(0) before barrier)

  for (int i = 0; i < n; ++i) {
    const int k0 = ktOf(i) * 32;
    bf16* Ks = lds_ + buf * 32768;
    bf16* Vs = Ks + 16384;
    // ---- prefetch next worklist tile into the other buffer ----
    if (i + 1 < n) STAGE(lds_ + (buf ^ 1) * 32768, ktOf(i + 1) * 32);

    const bool active = !CAUSAL || ((w >= 4) == (i >= nLo));
    if (active) {
      // ---- S^T = K * Q^T ----
      f32x4 sa0 = (f32x4){0.f, 0.f, 0.f, 0.f};
      f32x4 sa1 = (f32x4){0.f, 0.f, 0.f, 0.f};
      __builtin_amdgcn_s_setprio(1);
#pragma unroll
      for (int s = 0; s < 16; ++s) {
        const int lc = s * 4 + quad;
        const int swz = ((lc & ~7) | ((lc ^ l15) & 7)) * 8;
        bf16x8 a0 = *(const bf16x8*)&Ks[l15 * 512 + swz];
        bf16x8 a1 = *(const bf16x8*)&Ks[(16 + l15) * 512 + swz];
        sa0 = MFMA16(a0, qf[s], sa0);
        sa1 = MFMA16(a1, qf[s], sa1);
      }
      __builtin_amdgcn_s_setprio(0);

      // ---- online softmax (fully wave-local; lane's q-row = qwb + l15) ----
      float sv[8];
      {
        const int qrow = qwb + l15;
        const bool needMask = CAUSAL && (k0 + 31 > qwb);
#pragma unroll
        for (int kt2 = 0; kt2 < 2; ++kt2)
#pragma unroll
          for (int r = 0; r < 4; ++r) {
            float s = (kt2 == 0) ? sa0[r] : sa1[r];
            if (needMask) {
              int key = k0 + kt2 * 16 + quad * 4 + r;
              if (key > qrow) s = -1e30f;
            }
            sv[kt2 * 4 + r] = s;
          }
      }
      float tm = sv[0];
#pragma unroll
      for (int i2 = 1; i2 < 8; ++i2) tm = fmaxf(tm, sv[i2]);
      tm = fmaxf(tm, __shfl_xor(tm, 16));
      tm = fmaxf(tm, __shfl_xor(tm, 32));
      const float mn = fmaxf(m, tm);
      const float alpha = __expf(m - mn);
      m = mn;
      float pf[8];
      float ts = 0.f;
#pragma unroll
      for (int i2 = 0; i2 < 8; ++i2) { pf[i2] = __expf(sv[i2] - mn); ts += pf[i2]; }
      ts += __shfl_xor(ts, 16);
      ts += __shfl_xor(ts, 32);
      l = l * alpha + ts;
      if (__ballot(alpha < 0.99999f)) {
#pragma unroll
        for (int dt = 0; dt < 32; ++dt)
#pragma unroll
          for (int r = 0; r < 4; ++r) o[dt][r] *= alpha;
      }

      // ---- P^T (C-layout) -> B-operand frag via ds_bpermute, no LDS ----
      bf16x8 pb;
#pragma unroll
      for (int jj = 0; jj < 8; ++jj) {
        const int r_ = jj & 3;
        const int sl = (jj < 4) ? laneA4 : laneB4;
        float v0 = __int_as_float(__builtin_amdgcn_ds_bpermute(sl, __float_as_int(pf[r_])));
        float v1 = __int_as_float(__builtin_amdgcn_ds_bpermute(sl, __float_as_int(pf[4 + r_])));
        pb[jj] = (bf16)(quad < 2 ? v0 : v1);
      }

      // ---- O^T += V^T * P (swizzled V read: conflict-free b128) ----
      __builtin_amdgcn_s_setprio(1);
#pragma unroll
      for (int dt = 0; dt < 32; ++dt) {
        bf16x8 a = *(const bf16x8*)&Vs[(dt * 16 + l15) * 32 + vsw];
        o[dt] = MFMA16(a, pb, o[dt]);
      }
      __builtin_amdgcn_s_setprio(0);
    }

    __syncthreads();  // readers of buf done + prefetch into buf^1 drained (single barrier/tile)
    buf ^= 1;
  }

  // ---- epilogue: normalize by 1/l, write partial + (m,l) ----
  const float inv = 1.f / l;
  if (lane < 16 && quad == 0) ml[((size_t)z * NB + b) * NS + qwb + lane] = make_float2(m, l);
  bf16* Ow = lds_ + w * 8192;  // 16 KB per wave: [16 q][512 d] (whole 128 KB reused)
#pragma unroll
  for (int dt = 0; dt < 32; ++dt) {
    bf16x4 v;
#pragma unroll
    for (int r = 0; r < 4; ++r) v[r] = (bf16)(o[dt][r] * inv);
    *(bf16x4*)&Ow[l15 * 512 + dt * 16 + quad * 4] = v;
  }
  bf16* Og = (z ? O1 : O0) + ((size_t)b * NS + qwb) * ND;
#pragma unroll
  for (int it = 0; it < 16; ++it) {
    bf16x8 row = *(const bf16x8*)&Ow[it * 512 + lane * 8];
    *(bf16x8*)&Og[(size_t)it * ND + lane * 8] = row;
  }
}

// ---------------- merge two K-split partials: O0 = c0*O0 + c1*O1 ----------------
__global__ void k_merge(bf16* __restrict__ O0, const bf16* __restrict__ O1,
                        const float2* __restrict__ ml) {
  size_t i = ((size_t)blockIdx.x * 256 + threadIdx.x) * 8;
  int row = (int)(i >> 9);  // / 512
  float2 a = ml[row];
  float2 c = ml[(size_t)NB * NS + row];
  float M = fmaxf(a.x, c.x);
  float w0 = __expf(a.x - M) * a.y;
  float w1 = __expf(c.x - M) * c.y;
  float den = 1.f / (w0 + w1);
  float c0 = w0 * den, c1 = w1 * den;
  bf16x8 v0 = *(const bf16x8*)(O0 + i);
  bf16x8 v1 = *(const bf16x8*)(O1 + i);
  bf16x8 ov;
#pragma unroll
  for (int k = 0; k < 8; ++k) ov[k] = (bf16)(c0 * (float)v0[k] + c1 * (float)v1[k]);
  *(bf16x8*)(O0 + i) = ov;
}

// ---------------- NT GEMM (r12: double-buffered, one barrier per k-step) ----------------
// Out[M,N] = A[M,K] * W[N,K]^T (+bias)(+relu)(+res)(+LN stats)
template <int RES_MODE, bool HAS_BIAS, bool RELU, bool STATS>
__global__ __launch_bounds__(256) void k_gemm(const bf16* __restrict__ A, const bf16* __restrict__ W,
                                              const bf16* __restrict__ resid,
                                              const float* __restrict__ bias, bf16* __restrict__ Out,
                                              float* __restrict__ stats, int M, int N, int K,
                                              int rowOfs) {
  __shared__ bf16 As[2][128 * 64];
  __shared__ bf16 Ws[2][128 * 64];
  const int tid = threadIdx.x;
  const int w = tid >> 6, lane = tid & 63, quad = lane >> 4, l15 = lane & 15;
  const int m0 = blockIdx.x * 128, n0 = blockIdx.y * 128;
  const int wr = (w >> 1) * 64, wc = (w & 1) * 64;
  const int arow = lane >> 3, acol = (lane & 7) * 8;

  f32x4 acc[16];
#pragma unroll
  for (int i = 0; i < 16; ++i) acc[i] = (f32x4){0.f, 0.f, 0.f, 0.f};

  // stage one 128x64 A-tile + W-tile into buffer bf at k-offset k0
  auto STAGE = [&](int bf, int k0) {
#pragma unroll
    for (int i = 0; i < 4; ++i) {
      const int rbase = (w * 4 + i) * 8 + arow;
      async_copy16(&As[bf][(w * 4 + i) * 512], A + (size_t)(m0 + rbase) * K + k0 + acol);
      async_copy16(&Ws[bf][(w * 4 + i) * 512], W + (size_t)(n0 + rbase) * K + k0 + acol);
    }
  };

  int buf = 0;
  STAGE(0, 0);
  __syncthreads();  // prologue staging drained (vmcnt(0) before barrier)

  for (int k0 = 0; k0 < K; k0 += 64) {
    if (k0 + 64 < K) STAGE(buf ^ 1, k0 + 64);  // prefetch next k-step during compute
#pragma unroll
    for (int s = 0; s < 2; ++s) {
      bf16x8 af[4], bw[4];
#pragma unroll
      for (int i = 0; i < 4; ++i) af[i] = *(const bf16x8*)&As[buf][(wr + i * 16 + l15) * 64 + s * 32 + quad * 8];
#pragma unroll
      for (int jj = 0; jj < 4; ++jj) bw[jj] = *(const bf16x8*)&Ws[buf][(wc + jj * 16 + l15) * 64 + s * 32 + quad * 8];
#pragma unroll
      for (int i = 0; i < 4; ++i)
#pragma unroll
        for (int jj = 0; jj < 4; ++jj) acc[i * 4 + jj] = MFMA16(af[i], bw[jj], acc[i * 4 + jj]);
    }
    __syncthreads();  // readers of buf done + prefetch into buf^1 drained
    buf ^= 1;
  }

  float lsum = 0.f, lsq = 0.f;
#pragma unroll
  for (int i = 0; i < 4; ++i)
#pragma unroll
    for (int jj = 0; jj < 4; ++jj)
#pragma unroll
      for (int r = 0; r < 4; ++r) {
        int row = m0 + wr + i * 16 + quad * 4 + r;
        int col = n0 + wc + jj * 16 + l15;
        float v = acc[i * 4 + jj][r];
        if (HAS_BIAS) v += bias[col];
        if (RELU) v = fmaxf(v, 0.f);
        if (RES_MODE == 2) v += (float)resid[(size_t)row * N + col];
        Out[(size_t)row * N + col] = (bf16)v;
        if (STATS) { lsum += v; lsq += v * v; }
      }

  if (STATS) {
    __syncthreads();
    float* red = (float*)As;
    red[tid] = lsum;
    red[256 + tid] = lsq;
    __syncthreads();
    for (int off = 128; off > 0; off >>= 1) {
      if (tid < off) { red[tid] += red[tid + off]; red[256 + tid] += red[256 + tid + off]; }
      __syncthreads();
    }
    if (tid == 0) {
      int bidx = (rowOfs + m0) >> 12;  // 4096 rows per batch
      atomicAdd(&stats[bidx * 2], red[0]);
      atomicAdd(&stats[bidx * 2 + 1], red[256]);
    }
  }
}

// ---------------- LayerNorm apply over (S,D) jointly per batch ----------------
template <bool FINAL>
__global__ void k_ln(const bf16* __restrict__ T, const float* __restrict__ stats,
                     const void* __restrict__ gp, const void* __restrict__ bp,
                     void* __restrict__ outp, const unsigned* __restrict__ flag) {
  const float invN = 1.f / 2097152.f;
  size_t i = ((size_t)(blockIdx.x * 256 + threadIdx.x)) * 8;
  int b = (int)(i >> 21);
  int sd = (int)(i & 2097151);
  float mu = stats[b * 2] * invN;
  float var = stats[b * 2 + 1] * invN - mu * mu;
  float rs = rsqrtf(var + 1e-5f);
  bool f32m = (*flag != 0);
  bf16x8 tv = *(const bf16x8*)(T + i);
  float gv[8], bv[8];
  if (f32m) {
    float4 a = *(const float4*)((const float*)gp + sd), c = *(const float4*)((const float*)gp + sd + 4);
    gv[0] = a.x; gv[1] = a.y; gv[2] = a.z; gv[3] = a.w; gv[4] = c.x; gv[5] = c.y; gv[6] = c.z; gv[7] = c.w;
    float4 e = *(const float4*)((const float*)bp + sd), f = *(const float4*)((const float*)bp + sd + 4);
    bv[0] = e.x; bv[1] = e.y; bv[2] = e.z; bv[3] = e.w; bv[4] = f.x; bv[5] = f.y; bv[6] = f.z; bv[7] = f.w;
  } else {
    bf16x8 g8 = *(const bf16x8*)((const bf16*)gp + sd);
    bf16x8 b8 = *(const bf16x8*)((const bf16*)bp + sd);
#pragma unroll
    for (int k = 0; k < 8; ++k) { gv[k] = (float)g8[k]; bv[k] = (float)b8[k]; }
  }
  float ov[8];
#pragma unroll
  for (int k = 0; k < 8; ++k) ov[k] = ((float)tv[k] - mu) * rs * gv[k] + bv[k];
  if (FINAL && f32m) {
    float4 o0 = {ov[0], ov[1], ov[2], ov[3]}, o1 = {ov[4], ov[5], ov[6], ov[7]};
    *(float4*)((float*)outp + i) = o0;
    *(float4*)((float*)outp + i + 4) = o1;
  } else {
    bf16x8 o8;
#pragma unroll
    for (int k = 0; k < 8; ++k) o8[k] = (bf16)ov[k];
    *(bf16x8*)((bf16*)outp + i) = o8;
  }
}

// ---------------- fused LayerNorm + transpose: X = LN(T), XT = X^T (k-swizzled) ----------------
__global__ void k_ln_t(const bf16* __restrict__ T, const float* __restrict__ stats,
                       const void* __restrict__ gp, const void* __restrict__ bp,
                       bf16* __restrict__ X, bf16* __restrict__ XT,
                       const unsigned* __restrict__ flag) {
  __shared__ bf16 t[64][72];
  const float invN = 1.f / 2097152.f;
  const int b = blockIdx.z, s0 = blockIdx.x * 64, d0 = blockIdx.y * 64;
  const int tid = threadIdx.x;
  const float mu = stats[b * 2] * invN;
  const float var = stats[b * 2 + 1] * invN - mu * mu;
  const float rs = rsqrtf(var + 1e-5f);
  const bool f32m = (*flag != 0);
#pragma unroll
  for (int it = 0; it < 2; ++it) {
    int slot = it * 256 + tid;
    int r = slot >> 3, c = (slot & 7) * 8;
    size_t idx = ((size_t)b * NS + s0 + r) * ND + d0 + c;
    size_t pidx = (size_t)(s0 + r) * ND + d0 + c;
    bf16x8 tv = *(const bf16x8*)&T[idx];
    float gv[8], bv[8];
    if (f32m) {
      float4 a = *(const float4*)((const float*)gp + pidx), cc = *(const float4*)((const float*)gp + pidx + 4);
      gv[0] = a.x; gv[1] = a.y; gv[2] = a.z; gv[3] = a.w; gv[4] = cc.x; gv[5] = cc.y; gv[6] = cc.z; gv[7] = cc.w;
      float4 e = *(const float4*)((const float*)bp + pidx), f = *(const float4*)((const float*)bp + pidx + 4);
      bv[0] = e.x; bv[1] = e.y; bv[2] = e.z; bv[3] = e.w; bv[4] = f.x; bv[5] = f.y; bv[6] = f.z; bv[7] = f.w;
    } else {
      bf16x8 g8 = *(const bf16x8*)((const bf16*)gp + pidx);
      bf16x8 b8 = *(const bf16x8*)((const bf16*)bp + pidx);
#pragma unroll
      for (int k = 0; k < 8; ++k) { gv[k] = (float)g8[k]; bv[k] = (float)b8[k]; }
    }
    bf16x8 ov;
#pragma unroll
    for (int k = 0; k < 8; ++k) ov[k] = (bf16)(((float)tv[k] - mu) * rs * gv[k] + bv[k]);
    *(bf16x8*)&X[idx] = ov;
    *(bf16x8*)&t[r][c] = ov;
  }
  __syncthreads();
#pragma unroll
  for (int it = 0; it < 2; ++it) {
    int slot = it * 256 + tid;
    int r = slot >> 3, c = (slot & 7) * 8;  // r = local dim, c = local seq base
    bf16x8 v;
#pragma unroll
    for (int k = 0; k < 8; ++k) v[k] = t[c + k][r];
    *(bf16x8*)&XT[((size_t)b * ND + d0 + r) * NS + s0 + vswz_col(c, r)] = v;
  }
}

// ---------------- launch ----------------
extern "C" void kernel_launch(void* const* d_in, const int* in_sizes, int n_in, void* d_out,
                              int out_size, void* d_ws, size_t ws_size, hipStream_t stream) {
  (void)in_sizes; (void)n_in; (void)out_size;
  const void* x_raw = d_in[0];
  const void* enc_raw = d_in[1];
  const void* Wo1_raw = d_in[2];
  const void* Wo2_raw = d_in[3];
  const void* g1_raw = d_in[4];
  const void* bb1_raw = d_in[5];
  const void* g2_raw = d_in[6];
  const void* bb2_raw = d_in[7];
  const void* W1_raw = d_in[8];
  const void* bias1_raw = d_in[9];
  const void* W2_raw = d_in[10];
  const void* bias2_raw = d_in[11];

  char* w = (char*)d_ws;
  unsigned* flag = (unsigned*)(w + 0);
  float* stats = (float*)(w + 16);  // 3 stages x [B][2]
  float* b1f = (float*)(w + 1024);
  float* b2f = (float*)(w + 1024 + 8192);
  size_t off = 16384;
  const size_t nBSD = (size_t)NB * NS * ND;
  bf16* Wo1b = (bf16*)(w + off); off += (size_t)ND * ND * 2;
  bf16* Wo2b = (bf16*)(w + off); off += (size_t)ND * ND * 2;
  bf16* W1b = (bf16*)(w + off); off += (size_t)NF * ND * 2;
  bf16* W2b = (bf16*)(w + off); off += (size_t)ND * NF * 2;
  bf16* xb = (bf16*)(w + off); off += nBSD * 2;   // x bf16, later enc
  bf16* Ab = (bf16*)(w + off); off += nBSD * 2;
  bf16* Tb = (bf16*)(w + off); off += nBSD * 2;
  bf16* X1b = (bf16*)(w + off); off += nBSD * 2;
  bf16* Hb = (bf16*)(w + off);  // FFN hidden; attn partial-1 + ml earlier
  const size_t hbFull = (size_t)NB * NS * NF * 2;  // 64 MB (full-M FFN)
  const size_t hbHalf = hbFull / 2;                // 32 MB (2-chunk FFN)
  const bool ffnFull = (ws_size >= off + hbFull);
  if (!ffnFull && ws_size < off + hbHalf) return;

  bf16* O1b = Hb;                                 // partial-1 region (Hb dead until FFN)
  float2* mlb = (float2*)((char*)Hb + nBSD * 2);  // 2*B*S float2 = 256 KB

  hipMemsetAsync(stats, 0, 24 * sizeof(float), stream);
  k_detect<<<1, 256, 0, stream>>>((const unsigned short*)x_raw, flag);

  k_norm_bf16<<<(int)(nBSD / 2048), 256, 0, stream>>>(x_raw, xb, flag, (int)nBSD);
  k_norm_bf16<<<(ND * ND) / 2048, 256, 0, stream>>>(Wo1_raw, Wo1b, flag, ND * ND);
  k_norm_bf16<<<(ND * ND) / 2048, 256, 0, stream>>>(Wo2_raw, Wo2b, flag, ND * ND);
  k_norm_bf16<<<(NF * ND) / 2048, 256, 0, stream>>>(W1_raw, W1b, flag, NF * ND);
  k_norm_bf16<<<(NF * ND) / 2048, 256, 0, stream>>>(W2_raw, W2b, flag, ND * NF);
  k_norm_f32<<<8, 256, 0, stream>>>(bias1_raw, b1f, flag, NF);
  k_norm_f32<<<2, 256, 0, stream>>>(bias2_raw, b2f, flag, ND);

  // 1) causal self-attention + Wo1 + residual(x) + LN1 (fused with transpose for cross-attn V)
  k_transpose<<<dim3(NS / 64, ND / 64, NB), 256, 0, stream>>>(xb, Tb);  // x^T (swizzled) as V
  k_attn8<true><<<256, 512, 0, stream>>>(xb, xb, Tb, Ab, O1b, mlb);
  k_merge<<<(int)(nBSD / 2048), 256, 0, stream>>>(Ab, O1b, mlb);
  k_gemm<2, false, false, true><<<dim3(128, 4), 256, 0, stream>>>(Ab, Wo1b, xb, nullptr, Tb,
                                                                  stats + 0, NB * NS, ND, ND, 0);
  k_ln_t<<<dim3(NS / 64, ND / 64, NB), 256, 0, stream>>>(Tb, stats + 0, g1_raw, bb1_raw, X1b, Ab,
                                                         flag);  // X1 -> X1b, X1^T (swizzled) -> Ab
  k_norm_bf16<<<(int)(nBSD / 2048), 256, 0, stream>>>(enc_raw, xb, flag, (int)nBSD);  // xb := enc

  // 2) cross attention (q=k=enc, v=X1) + Wo2 + residual(X1) + LN2
  k_attn8<false><<<256, 512, 0, stream>>>(xb, xb, Ab, Tb, O1b, mlb);  // O0 -> Tb
  k_merge<<<(int)(nBSD / 2048), 256, 0, stream>>>(Tb, O1b, mlb);
  k_gemm<2, false, false, true><<<dim3(128, 4), 256, 0, stream>>>(Tb, Wo2b, X1b, nullptr, Ab,
                                                                  stats + 8, NB * NS, ND, ND, 0);
  k_ln<false><<<(int)(nBSD / 2048), 256, 0, stream>>>(Ab, stats + 8, g2_raw, bb2_raw, X1b, flag);
  // X1b now holds X2

  // 3) FFN + residual(X2) + LN (ln2 params). Full-M single pass if ws allows (FFN2: 2 blocks/CU).
  const int nChunk = ffnFull ? 1 : 2;
  const int rows = ffnFull ? (NB * NS) : 8192;
  for (int c = 0; c < nChunk; ++c) {
    size_t ro = (size_t)c * rows;
    k_gemm<0, true, true, false><<<dim3(rows / 128, 16), 256, 0, stream>>>(
        X1b + ro * ND, W1b, nullptr, b1f, Hb, nullptr, rows, NF, ND, 0);
    k_gemm<2, true, false, true><<<dim3(rows / 128, 4), 256, 0, stream>>>(
        Hb, W2b, X1b + ro * ND, b2f, Tb + ro * ND, stats + 16, rows, ND, NF, (int)ro);
  }
  k_ln<true><<<(int)(nBSD / 2048), 256, 0, stream>>>(Tb, stats + 16, g2_raw, bb2_raw, d_out, flag);
}

// Round 10
// 754.505 us; speedup vs baseline: 1.8336x; 1.0051x over previous
//
// TransformerDecoderBlock on MI355X (gfx950) — round 13: fuse k_merge into k_gemm A-staging.
// r12 verified: attn r8 core 217us/28MB FETCH; gemm dbuf +25us. Non-attn = 324us; the two
// k_merge passes (~192MB stream each, ~30us) have a single consumer — the following gemm.
// k_gemm<MERGE_A>: A-operand reg-staged as merge(O0,O1,ml) with k_merge's exact math, ds_write
// to the same LDS slot the async path used; W stays async_copy16. 8 k-steps x ~500cy load stall
// partially hidden by 2 blocks/CU. Attn/FFN paths unchanged.
#include <hip/hip_runtime.h>
#include <cstdint>
#include <cstddef>

#define NB 4
#define NS 4096
#define ND 512
#define NF 2048

typedef __bf16 bf16;
typedef __attribute__((ext_vector_type(8))) __bf16 bf16x8;
typedef __attribute__((ext_vector_type(4))) __bf16 bf16x4;
typedef __attribute__((ext_vector_type(4))) float f32x4;

#define MFMA16(a, b, c) __builtin_amdgcn_mfma_f32_16x16x32_bf16((a), (b), (c), 0, 0, 0)

// Async global->LDS, 16B per lane. LDS dest is wave-uniform base; lane i lands at base+16*i.
__device__ __forceinline__ void async_copy16(void* lds, const void* g) {
  __builtin_amdgcn_global_load_lds(
      (__attribute__((address_space(1))) unsigned int*)(uintptr_t)g,
      (__attribute__((address_space(3))) unsigned int*)(unsigned)(uintptr_t)lds,
      16, 0, 0);
}

// V^T global k-swizzle: within each 32-k block, 8-elem chunk c of dim-row d is stored at
// chunk ((c + (d>>1)) & 3). Makes the attention PV ds_read_b128 conflict-free.
__device__ __forceinline__ int vswz_col(int c /*mult of 8 in [0,64)*/, int dloc) {
  return (c & ~31) | (((((c >> 3) & 3) + ((dloc >> 1) & 3)) & 3) << 3);
}

// ---------------- dtype detect ----------------
__global__ void k_detect(const unsigned short* __restrict__ x, unsigned* __restrict__ flag) {
  __shared__ int cnt;
  if (threadIdx.x == 0) cnt = 0;
  __syncthreads();
  int bad = 0;
  for (int i = threadIdx.x; i < 2048; i += 256) {
    unsigned e = (x[i] >> 7) & 0xFF;
    if (e < 100 || e > 140) bad++;
  }
  atomicAdd(&cnt, bad);
  __syncthreads();
  if (threadIdx.x == 0) *flag = (cnt > 200) ? 1u : 0u;  // 1 => inputs are f32
}

// ---------------- input normalization ----------------
__global__ void k_norm_bf16(const void* __restrict__ src, bf16* __restrict__ dst,
                            const unsigned* __restrict__ flag, int n) {
  int i = (blockIdx.x * 256 + threadIdx.x) * 8;
  if (i >= n) return;
  if (*flag) {
    const float* s = (const float*)src;
    float4 a = *(const float4*)(s + i);
    float4 c = *(const float4*)(s + i + 4);
    bf16x8 v;
    v[0] = (bf16)a.x; v[1] = (bf16)a.y; v[2] = (bf16)a.z; v[3] = (bf16)a.w;
    v[4] = (bf16)c.x; v[5] = (bf16)c.y; v[6] = (bf16)c.z; v[7] = (bf16)c.w;
    *(bf16x8*)(dst + i) = v;
  } else {
    *(uint4*)(dst + i) = *(const uint4*)((const bf16*)src + i);
  }
}

__global__ void k_norm_f32(const void* __restrict__ src, float* __restrict__ dst,
                           const unsigned* __restrict__ flag, int n) {
  int i = blockIdx.x * 256 + threadIdx.x;
  if (i >= n) return;
  dst[i] = (*flag) ? ((const float*)src)[i] : (float)((const bf16*)src)[i];
}

// ---------------- transpose [B][S][D] -> [B][D][S] (bf16), k-swizzled output ----------------
__global__ void k_transpose(const bf16* __restrict__ in, bf16* __restrict__ out) {
  __shared__ bf16 t[64][72];
  const int b = blockIdx.z, s0 = blockIdx.x * 64, d0 = blockIdx.y * 64;
  const int tid = threadIdx.x;
#pragma unroll
  for (int it = 0; it < 2; ++it) {
    int slot = it * 256 + tid;
    int r = slot >> 3, c = (slot & 7) * 8;
    *(bf16x8*)&t[r][c] = *(const bf16x8*)&in[((size_t)b * NS + s0 + r) * ND + d0 + c];
  }
  __syncthreads();
#pragma unroll
  for (int it = 0; it < 2; ++it) {
    int slot = it * 256 + tid;
    int r = slot >> 3, c = (slot & 7) * 8;  // r = local dim, c = local seq base
    bf16x8 v;
#pragma unroll
    for (int k = 0; k < 8; ++k) v[k] = t[c + k][r];
    *(bf16x8*)&out[((size_t)b * ND + d0 + r) * NS + s0 + vswz_col(c, r)] = v;
  }
}

// ---------------- flash attention — r8 core (verified): pipelined + causal diagonal pairing ----
// Grid: 256 blocks x 512 threads (8 waves). slot = blkid&7 -> (b = slot>>1, z = slot&1).
// Cross: q0 = (blkid>>3)*128, all 8 waves, 64 tiles (z-split of 128).
// Causal: j = blkid>>3 in [0,32); waves 0-3 own rows [64j, 64j+64), waves 4-7 own mirror rows
// [4032-64j, 4096-64j). Worklist: nLo = j+1 lo tiles then 64-j hi tiles = 65 iters for every j.
template <bool CAUSAL>
__global__ __launch_bounds__(512, 2) void k_attn8(const bf16* __restrict__ Q,
                                                  const bf16* __restrict__ Km,
                                                  const bf16* __restrict__ Vt,
                                                  bf16* __restrict__ O0, bf16* __restrict__ O1,
                                                  float2* __restrict__ ml) {
  __shared__ bf16 lds_[32768 * 2];  // 128 KB: 2 x { Ks [32 x 512] (32KB) + Vs [512 x 32] (32KB) }

  const int tid = threadIdx.x;
  const int w = tid >> 6, lane = tid & 63, quad = lane >> 4, l15 = lane & 15;
  const int slot = blockIdx.x & 7;
  const int b = slot >> 1;
  const int z = slot & 1;
  const int j = (int)(blockIdx.x >> 3);

  // per-wave q-row base + worklist shape
  int qwb, nLo, n;
  if (CAUSAL) {
    nLo = j + 1;                 // lo-group tiles for this z (z picks which half-range)
    n = 65;                      // (j+1) + (64-j), constant for all j
    qwb = (w < 4) ? (64 * j + w * 16) : (4032 - 64 * j + (w - 4) * 16);
  } else {
    nLo = 1 << 30;
    n = 64;
    qwb = j * 128 + w * 16;
  }
  const int nHi = 64 - j;  // causal hi-group tiles for this z

  const bf16* Kg = Km + (size_t)b * NS * ND;
  const bf16* Vg = Vt + (size_t)b * ND * NS;

  // worklist item -> k-tile index
  auto ktOf = [&](int i) -> int {
    if (!CAUSAL) return z * 64 + i;
    return (i < nLo) ? (z * nLo + i) : (z * nHi + (i - nLo));
  };

  // ---- Q fragments in registers, pre-scaled by 1/sqrt(D) ----
  const bf16* Qg = Q + ((size_t)b * NS + qwb + l15) * ND;
  bf16x8 qf[16];
#pragma unroll
  for (int s = 0; s < 16; ++s) qf[s] = *(const bf16x8*)&Qg[s * 32 + quad * 8];
#pragma unroll
  for (int s = 0; s < 16; ++s)
#pragma unroll
    for (int jj = 0; jj < 8; ++jj) qf[s][jj] = (bf16)((float)qf[s][jj] * 0.044194173824159216f);

  f32x4 o[32];  // O^T: o[dt] -> (d = dt*16 + quad*4 + r, q = l15)
#pragma unroll
  for (int i = 0; i < 32; ++i) o[i] = (f32x4){0.f, 0.f, 0.f, 0.f};

  float m = -1e30f, l = 0.f;  // per-lane, q = l15 (replicated across quads)

  const int laneA4 = ((((quad * 2) & 3) * 16) + l15) * 4;
  const int laneB4 = ((((quad * 2 + 1) & 3) * 16) + l15) * 4;
  const int vsw = ((quad + ((l15 >> 1) & 3)) & 3) * 8;  // swizzled V chunk offset (elements)

  // stage tile (K rows w*4..w*4+3 with XOR-swizzle source; V^T 16-d groups, chunk-linear)
  auto STAGE = [&](bf16* base, int k0) {
#pragma unroll
    for (int i = 0; i < 4; ++i) {
      const int r = w * 4 + i;
      const int g = (lane & ~7) | ((lane ^ r) & 7);
      async_copy16(base + r * 512, Kg + (size_t)(k0 + r) * ND + g * 8);
    }
#pragma unroll
    for (int i = 0; i < 4; ++i) {
      const int d0 = (w * 4 + i) * 16;
      async_copy16(base + 16384 + d0 * 32, Vg + (size_t)(d0 + (lane >> 2)) * NS + k0 + (lane & 3) * 8);
    }
  };

  int buf = 0;
  STAGE(lds_, ktOf(0) * 32);
  __syncthreads();  // prologue staging drained (compiler emits vmcnt(0) before barrier)

  for (int i = 0; i < n; ++i) {
    const int k0 = ktOf(i) * 32;
    bf16* Ks = lds_ + buf * 32768;
    bf16* Vs = Ks + 16384;
    // ---- prefetch next worklist tile into the other buffer ----
    if (i + 1 < n) STAGE(lds_ + (buf ^ 1) * 32768, ktOf(i + 1) * 32);

    const bool active = !CAUSAL || ((w >= 4) == (i >= nLo));
    if (active) {
      // ---- S^T = K * Q^T ----
      f32x4 sa0 = (f32x4){0.f, 0.f, 0.f, 0.f};
      f32x4 sa1 = (f32x4){0.f, 0.f, 0.f, 0.f};
      __builtin_amdgcn_s_setprio(1);
#pragma unroll
      for (int s = 0; s < 16; ++s) {
        const int lc = s * 4 + quad;
        const int swz = ((lc & ~7) | ((lc ^ l15) & 7)) * 8;
        bf16x8 a0 = *(const bf16x8*)&Ks[l15 * 512 + swz];
        bf16x8 a1 = *(const bf16x8*)&Ks[(16 + l15) * 512 + swz];
        sa0 = MFMA16(a0, qf[s], sa0);
        sa1 = MFMA16(a1, qf[s], sa1);
      }
      __builtin_amdgcn_s_setprio(0);

      // ---- online softmax (fully wave-local; lane's q-row = qwb + l15) ----
      float sv[8];
      {
        const int qrow = qwb + l15;
        const bool needMask = CAUSAL && (k0 + 31 > qwb);
#pragma unroll
        for (int kt2 = 0; kt2 < 2; ++kt2)
#pragma unroll
          for (int r = 0; r < 4; ++r) {
            float s = (kt2 == 0) ? sa0[r] : sa1[r];
            if (needMask) {
              int key = k0 + kt2 * 16 + quad * 4 + r;
              if (key > qrow) s = -1e30f;
            }
            sv[kt2 * 4 + r] = s;
          }
      }
      float tm = sv[0];
#pragma unroll
      for (int i2 = 1; i2 < 8; ++i2) tm = fmaxf(tm, sv[i2]);
      tm = fmaxf(tm, __shfl_xor(tm, 16));
      tm = fmaxf(tm, __shfl_xor(tm, 32));
      const float mn = fmaxf(m, tm);
      const float alpha = __expf(m - mn);
      m = mn;
      float pf[8];
      float ts = 0.f;
#pragma unroll
      for (int i2 = 0; i2 < 8; ++i2) { pf[i2] = __expf(sv[i2] - mn); ts += pf[i2]; }
      ts += __shfl_xor(ts, 16);
      ts += __shfl_xor(ts, 32);
      l = l * alpha + ts;
      if (__ballot(alpha < 0.99999f)) {
#pragma unroll
        for (int dt = 0; dt < 32; ++dt)
#pragma unroll
          for (int r = 0; r < 4; ++r) o[dt][r] *= alpha;
      }

      // ---- P^T (C-layout) -> B-operand frag via ds_bpermute, no LDS ----
      bf16x8 pb;
#pragma unroll
      for (int jj = 0; jj < 8; ++jj) {
        const int r_ = jj & 3;
        const int sl = (jj < 4) ? laneA4 : laneB4;
        float v0 = __int_as_float(__builtin_amdgcn_ds_bpermute(sl, __float_as_int(pf[r_])));
        float v1 = __int_as_float(__builtin_amdgcn_ds_bpermute(sl, __float_as_int(pf[4 + r_])));
        pb[jj] = (bf16)(quad < 2 ? v0 : v1);
      }

      // ---- O^T += V^T * P (swizzled V read: conflict-free b128) ----
      __builtin_amdgcn_s_setprio(1);
#pragma unroll
      for (int dt = 0; dt < 32; ++dt) {
        bf16x8 a = *(const bf16x8*)&Vs[(dt * 16 + l15) * 32 + vsw];
        o[dt] = MFMA16(a, pb, o[dt]);
      }
      __builtin_amdgcn_s_setprio(0);
    }

    __syncthreads();  // readers of buf done + prefetch into buf^1 drained (single barrier/tile)
    buf ^= 1;
  }

  // ---- epilogue: normalize by 1/l, write partial + (m,l) ----
  const float inv = 1.f / l;
  if (lane < 16 && quad == 0) ml[((size_t)z * NB + b) * NS + qwb + lane] = make_float2(m, l);
  bf16* Ow = lds_ + w * 8192;  // 16 KB per wave: [16 q][512 d] (whole 128 KB reused)
#pragma unroll
  for (int dt = 0; dt < 32; ++dt) {
    bf16x4 v;
#pragma unroll
    for (int r = 0; r < 4; ++r) v[r] = (bf16)(o[dt][r] * inv);
    *(bf16x4*)&Ow[l15 * 512 + dt * 16 + quad * 4] = v;
  }
  bf16* Og = (z ? O1 : O0) + ((size_t)b * NS + qwb) * ND;
#pragma unroll
  for (int it = 0; it < 16; ++it) {
    bf16x8 row = *(const bf16x8*)&Ow[it * 512 + lane * 8];
    *(bf16x8*)&Og[(size_t)it * ND + lane * 8] = row;
  }
}

// ---------------- NT GEMM (r13: dbuf + optional fused K-split merge on the A operand) --------
// Out[M,N] = mergeA(A0,A1,ml) * W[N,K]^T (+bias)(+relu)(+res)(+LN stats)
template <int RES_MODE, bool HAS_BIAS, bool RELU, bool STATS, bool MERGE_A>
__global__ __launch_bounds__(256) void k_gemm(const bf16* __restrict__ A,
                                              const bf16* __restrict__ A1,
                                              const float2* __restrict__ mlp,
                                              const bf16* __restrict__ W,
                                              const bf16* __restrict__ resid,
                                              const float* __restrict__ bias, bf16* __restrict__ Out,
                                              float* __restrict__ stats, int M, int N, int K,
                                              int rowOfs) {
  __shared__ bf16 As[2][128 * 64];
  __shared__ bf16 Ws[2][128 * 64];
  const int tid = threadIdx.x;
  const int w = tid >> 6, lane = tid & 63, quad = lane >> 4, l15 = lane & 15;
  const int m0 = blockIdx.x * 128, n0 = blockIdx.y * 128;
  const int wr = (w >> 1) * 64, wc = (w & 1) * 64;
  const int arow = lane >> 3, acol = (lane & 7) * 8;

  f32x4 acc[16];
#pragma unroll
  for (int i = 0; i < 16; ++i) acc[i] = (f32x4){0.f, 0.f, 0.f, 0.f};

  // stage one 128x64 A-tile + W-tile into buffer bf at k-offset k0
  auto STAGE = [&](int bf, int k0) {
#pragma unroll
    for (int i = 0; i < 4; ++i) {
      const int rbase = (w * 4 + i) * 8 + arow;
      if constexpr (!MERGE_A) {
        async_copy16(&As[bf][(w * 4 + i) * 512], A + (size_t)(m0 + rbase) * K + k0 + acol);
      } else {
        const int row = m0 + rbase;
        float2 a = mlp[row];
        float2 c = mlp[(size_t)NB * NS + row];
        float Mx = fmaxf(a.x, c.x);
        float w0 = __expf(a.x - Mx) * a.y;
        float w1 = __expf(c.x - Mx) * c.y;
        float den = 1.f / (w0 + w1);
        float c0 = w0 * den, c1 = w1 * den;
        bf16x8 v0 = *(const bf16x8*)(A + (size_t)row * K + k0 + acol);
        bf16x8 v1 = *(const bf16x8*)(A1 + (size_t)row * K + k0 + acol);
        bf16x8 ov;
#pragma unroll
        for (int k = 0; k < 8; ++k) ov[k] = (bf16)(c0 * (float)v0[k] + c1 * (float)v1[k]);
        *(bf16x8*)&As[bf][(w * 4 + i) * 512 + lane * 8] = ov;
      }
      async_copy16(&Ws[bf][(w * 4 + i) * 512], W + (size_t)(n0 + rbase) * K + k0 + acol);
    }
  };

  int buf = 0;
  STAGE(0, 0);
  __syncthreads();  // prologue staging drained (vmcnt(0)+lgkmcnt(0) before barrier)

  for (int k0 = 0; k0 < K; k0 += 64) {
    if (k0 + 64 < K) STAGE(buf ^ 1, k0 + 64);  // prefetch next k-step during compute
#pragma unroll
    for (int s = 0; s < 2; ++s) {
      bf16x8 af[4], bw[4];
#pragma unroll
      for (int i = 0; i < 4; ++i) af[i] = *(const bf16x8*)&As[buf][(wr + i * 16 + l15) * 64 + s * 32 + quad * 8];
#pragma unroll
      for (int jj = 0; jj < 4; ++jj) bw[jj] = *(const bf16x8*)&Ws[buf][(wc + jj * 16 + l15) * 64 + s * 32 + quad * 8];
#pragma unroll
      for (int i = 0; i < 4; ++i)
#pragma unroll
        for (int jj = 0; jj < 4; ++jj) acc[i * 4 + jj] = MFMA16(af[i], bw[jj], acc[i * 4 + jj]);
    }
    __syncthreads();  // readers of buf done + prefetch into buf^1 drained
    buf ^= 1;
  }

  float lsum = 0.f, lsq = 0.f;
#pragma unroll
  for (int i = 0; i < 4; ++i)
#pragma unroll
    for (int jj = 0; jj < 4; ++jj)
#pragma unroll
      for (int r = 0; r < 4; ++r) {
        int row = m0 + wr + i * 16 + quad * 4 + r;
        int col = n0 + wc + jj * 16 + l15;
        float v = acc[i * 4 + jj][r];
        if (HAS_BIAS) v += bias[col];
        if (RELU) v = fmaxf(v, 0.f);
        if (RES_MODE == 2) v += (float)resid[(size_t)row * N + col];
        Out[(size_t)row * N + col] = (bf16)v;
        if (STATS) { lsum += v; lsq += v * v; }
      }

  if (STATS) {
    __syncthreads();
    float* red = (float*)As;
    red[tid] = lsum;
    red[256 + tid] = lsq;
    __syncthreads();
    for (int off = 128; off > 0; off >>= 1) {
      if (tid < off) { red[tid] += red[tid + off]; red[256 + tid] += red[256 + tid + off]; }
      __syncthreads();
    }
    if (tid == 0) {
      int bidx = (rowOfs + m0) >> 12;  // 4096 rows per batch
      atomicAdd(&stats[bidx * 2], red[0]);
      atomicAdd(&stats[bidx * 2 + 1], red[256]);
    }
  }
}

// ---------------- LayerNorm apply over (S,D) jointly per batch ----------------
template <bool FINAL>
__global__ void k_ln(const bf16* __restrict__ T, const float* __restrict__ stats,
                     const void* __restrict__ gp, const void* __restrict__ bp,
                     void* __restrict__ outp, const unsigned* __restrict__ flag) {
  const float invN = 1.f / 2097152.f;
  size_t i = ((size_t)(blockIdx.x * 256 + threadIdx.x)) * 8;
  int b = (int)(i >> 21);
  int sd = (int)(i & 2097151);
  float mu = stats[b * 2] * invN;
  float var = stats[b * 2 + 1] * invN - mu * mu;
  float rs = rsqrtf(var + 1e-5f);
  bool f32m = (*flag != 0);
  bf16x8 tv = *(const bf16x8*)(T + i);
  float gv[8], bv[8];
  if (f32m) {
    float4 a = *(const float4*)((const float*)gp + sd), c = *(const float4*)((const float*)gp + sd + 4);
    gv[0] = a.x; gv[1] = a.y; gv[2] = a.z; gv[3] = a.w; gv[4] = c.x; gv[5] = c.y; gv[6] = c.z; gv[7] = c.w;
    float4 e = *(const float4*)((const float*)bp + sd), f = *(const float4*)((const float*)bp + sd + 4);
    bv[0] = e.x; bv[1] = e.y; bv[2] = e.z; bv[3] = e.w; bv[4] = f.x; bv[5] = f.y; bv[6] = f.z; bv[7] = f.w;
  } else {
    bf16x8 g8 = *(const bf16x8*)((const bf16*)gp + sd);
    bf16x8 b8 = *(const bf16x8*)((const bf16*)bp + sd);
#pragma unroll
    for (int k = 0; k < 8; ++k) { gv[k] = (float)g8[k]; bv[k] = (float)b8[k]; }
  }
  float ov[8];
#pragma unroll
  for (int k = 0; k < 8; ++k) ov[k] = ((float)tv[k] - mu) * rs * gv[k] + bv[k];
  if (FINAL && f32m) {
    float4 o0 = {ov[0], ov[1], ov[2], ov[3]}, o1 = {ov[4], ov[5], ov[6], ov[7]};
    *(float4*)((float*)outp + i) = o0;
    *(float4*)((float*)outp + i + 4) = o1;
  } else {
    bf16x8 o8;
#pragma unroll
    for (int k = 0; k < 8; ++k) o8[k] = (bf16)ov[k];
    *(bf16x8*)((bf16*)outp + i) = o8;
  }
}

// ---------------- fused LayerNorm + transpose: X = LN(T), XT = X^T (k-swizzled) ----------------
__global__ void k_ln_t(const bf16* __restrict__ T, const float* __restrict__ stats,
                       const void* __restrict__ gp, const void* __restrict__ bp,
                       bf16* __restrict__ X, bf16* __restrict__ XT,
                       const unsigned* __restrict__ flag) {
  __shared__ bf16 t[64][72];
  const float invN = 1.f / 2097152.f;
  const int b = blockIdx.z, s0 = blockIdx.x * 64, d0 = blockIdx.y * 64;
  const int tid = threadIdx.x;
  const float mu = stats[b * 2] * invN;
  const float var = stats[b * 2 + 1] * invN - mu * mu;
  const float rs = rsqrtf(var + 1e-5f);
  const bool f32m = (*flag != 0);
#pragma unroll
  for (int it = 0; it < 2; ++it) {
    int slot = it * 256 + tid;
    int r = slot >> 3, c = (slot & 7) * 8;
    size_t idx = ((size_t)b * NS + s0 + r) * ND + d0 + c;
    size_t pidx = (size_t)(s0 + r) * ND + d0 + c;
    bf16x8 tv = *(const bf16x8*)&T[idx];
    float gv[8], bv[8];
    if (f32m) {
      float4 a = *(const float4*)((const float*)gp + pidx), cc = *(const float4*)((const float*)gp + pidx + 4);
      gv[0] = a.x; gv[1] = a.y; gv[2] = a.z; gv[3] = a.w; gv[4] = cc.x; gv[5] = cc.y; gv[6] = cc.z; gv[7] = cc.w;
      float4 e = *(const float4*)((const float*)bp + pidx), f = *(const float4*)((const float*)bp + pidx + 4);
      bv[0] = e.x; bv[1] = e.y; bv[2] = e.z; bv[3] = e.w; bv[4] = f.x; bv[5] = f.y; bv[6] = f.z; bv[7] = f.w;
    } else {
      bf16x8 g8 = *(const bf16x8*)((const bf16*)gp + pidx);
      bf16x8 b8 = *(const bf16x8*)((const bf16*)bp + pidx);
#pragma unroll
      for (int k = 0; k < 8; ++k) { gv[k] = (float)g8[k]; bv[k] = (float)b8[k]; }
    }
    bf16x8 ov;
#pragma unroll
    for (int k = 0; k < 8; ++k) ov[k] = (bf16)(((float)tv[k] - mu) * rs * gv[k] + bv[k]);
    *(bf16x8*)&X[idx] = ov;
    *(bf16x8*)&t[r][c] = ov;
  }
  __syncthreads();
#pragma unroll
  for (int it = 0; it < 2; ++it) {
    int slot = it * 256 + tid;
    int r = slot >> 3, c = (slot & 7) * 8;  // r = local dim, c = local seq base
    bf16x8 v;
#pragma unroll
    for (int k = 0; k < 8; ++k) v[k] = t[c + k][r];
    *(bf16x8*)&XT[((size_t)b * ND + d0 + r) * NS + s0 + vswz_col(c, r)] = v;
  }
}

// ---------------- launch ----------------
extern "C" void kernel_launch(void* const* d_in, const int* in_sizes, int n_in, void* d_out,
                              int out_size, void* d_ws, size_t ws_size, hipStream_t stream) {
  (void)in_sizes; (void)n_in; (void)out_size;
  const void* x_raw = d_in[0];
  const void* enc_raw = d_in[1];
  const void* Wo1_raw = d_in[2];
  const void* Wo2_raw = d_in[3];
  const void* g1_raw = d_in[4];
  const void* bb1_raw = d_in[5];
  const void* g2_raw = d_in[6];
  const void* bb2_raw = d_in[7];
  const void* W1_raw = d_in[8];
  const void* bias1_raw = d_in[9];
  const void* W2_raw = d_in[10];
  const void* bias2_raw = d_in[11];

  char* w = (char*)d_ws;
  unsigned* flag = (unsigned*)(w + 0);
  float* stats = (float*)(w + 16);  // 3 stages x [B][2]
  float* b1f = (float*)(w + 1024);
  float* b2f = (float*)(w + 1024 + 8192);
  size_t off = 16384;
  const size_t nBSD = (size_t)NB * NS * ND;
  bf16* Wo1b = (bf16*)(w + off); off += (size_t)ND * ND * 2;
  bf16* Wo2b = (bf16*)(w + off); off += (size_t)ND * ND * 2;
  bf16* W1b = (bf16*)(w + off); off += (size_t)NF * ND * 2;
  bf16* W2b = (bf16*)(w + off); off += (size_t)ND * NF * 2;
  bf16* xb = (bf16*)(w + off); off += nBSD * 2;   // x bf16, later enc
  bf16* Ab = (bf16*)(w + off); off += nBSD * 2;
  bf16* Tb = (bf16*)(w + off); off += nBSD * 2;
  bf16* X1b = (bf16*)(w + off); off += nBSD * 2;
  bf16* Hb = (bf16*)(w + off);  // FFN hidden; attn partial-1 + ml earlier
  const size_t hbFull = (size_t)NB * NS * NF * 2;  // 64 MB (full-M FFN)
  const size_t hbHalf = hbFull / 2;                // 32 MB (2-chunk FFN)
  const bool ffnFull = (ws_size >= off + hbFull);
  if (!ffnFull && ws_size < off + hbHalf) return;

  bf16* O1b = Hb;                                 // partial-1 region (Hb dead until FFN)
  float2* mlb = (float2*)((char*)Hb + nBSD * 2);  // 2*B*S float2 = 256 KB

  hipMemsetAsync(stats, 0, 24 * sizeof(float), stream);
  k_detect<<<1, 256, 0, stream>>>((const unsigned short*)x_raw, flag);

  k_norm_bf16<<<(int)(nBSD / 2048), 256, 0, stream>>>(x_raw, xb, flag, (int)nBSD);
  k_norm_bf16<<<(ND * ND) / 2048, 256, 0, stream>>>(Wo1_raw, Wo1b, flag, ND * ND);
  k_norm_bf16<<<(ND * ND) / 2048, 256, 0, stream>>>(Wo2_raw, Wo2b, flag, ND * ND);
  k_norm_bf16<<<(NF * ND) / 2048, 256, 0, stream>>>(W1_raw, W1b, flag, NF * ND);
  k_norm_bf16<<<(NF * ND) / 2048, 256, 0, stream>>>(W2_raw, W2b, flag, ND * NF);
  k_norm_f32<<<8, 256, 0, stream>>>(bias1_raw, b1f, flag, NF);
  k_norm_f32<<<2, 256, 0, stream>>>(bias2_raw, b2f, flag, ND);

  // 1) causal self-attention + fused(merge + Wo1) + residual(x) + LN1 (+transpose for cross V)
  k_transpose<<<dim3(NS / 64, ND / 64, NB), 256, 0, stream>>>(xb, Tb);  // x^T (swizzled) as V
  k_attn8<true><<<256, 512, 0, stream>>>(xb, xb, Tb, Ab, O1b, mlb);
  k_gemm<2, false, false, true, true><<<dim3(128, 4), 256, 0, stream>>>(
      Ab, O1b, mlb, Wo1b, xb, nullptr, Tb, stats + 0, NB * NS, ND, ND, 0);
  k_ln_t<<<dim3(NS / 64, ND / 64, NB), 256, 0, stream>>>(Tb, stats + 0, g1_raw, bb1_raw, X1b, Ab,
                                                         flag);  // X1 -> X1b, X1^T (swizzled) -> Ab
  k_norm_bf16<<<(int)(nBSD / 2048), 256, 0, stream>>>(enc_raw, xb, flag, (int)nBSD);  // xb := enc

  // 2) cross attention (q=k=enc, v=X1) + fused(merge + Wo2) + residual(X1) + LN2
  k_attn8<false><<<256, 512, 0, stream>>>(xb, xb, Ab, Tb, O1b, mlb);  // O0 -> Tb
  k_gemm<2, false, false, true, true><<<dim3(128, 4), 256, 0, stream>>>(
      Tb, O1b, mlb, Wo2b, X1b, nullptr, Ab, stats + 8, NB * NS, ND, ND, 0);
  k_ln<false><<<(int)(nBSD / 2048), 256, 0, stream>>>(Ab, stats + 8, g2_raw, bb2_raw, X1b, flag);
  // X1b now holds X2

  // 3) FFN + residual(X2) + LN (ln2 params). Full-M single pass if ws allows (FFN2: 2 blocks/CU).
  const int nChunk = ffnFull ? 1 : 2;
  const int rows = ffnFull ? (NB * NS) : 8192;
  for (int c = 0; c < nChunk; ++c) {
    size_t ro = (size_t)c * rows;
    k_gemm<0, true, true, false, false><<<dim3(rows / 128, 16), 256, 0, stream>>>(
        X1b + ro * ND, nullptr, nullptr, W1b, nullptr, b1f, Hb, nullptr, rows, NF, ND, 0);
    k_gemm<2, true, false, true, false><<<dim3(rows / 128, 4), 256, 0, stream>>>(
        Hb, nullptr, nullptr, W2b, X1b + ro * ND, b2f, Tb + ro * ND, stats + 16, rows, ND, NF, (int)ro);
  }
  k_ln<true><<<(int)(nBSD / 2048), 256, 0, stream>>>(Tb, stats + 16, g2_raw, bb2_raw, d_out, flag);
}